// Round 2
// baseline (1095.476 us; speedup 1.0000x reference)
//
#include <hip/hip_runtime.h>
#include <hip/hip_bf16.h>

#define NTOK 16384
#define DIM  4096
#define NEXP 64

// ---------------------------------------------------------------------------
// Kernel 1: partial GEMM. One lane per token; per-lane 64 fp32 accumulators.
// W[e][k] is wave-uniform -> expect scalar (s_load) or broadcast vector loads.
// x streams per-lane: each lane's 16-float chunk = exactly one 64B line, so
// L1 captures full reuse despite per-lane row-major striding.
// K split across blocks for occupancy (512 blocks = 2 waves/SIMD).
// ---------------------------------------------------------------------------
__global__ __launch_bounds__(256, 2) void gate_gemm(const float* __restrict__ x,
                                                    const float* __restrict__ W,
                                                    float* __restrict__ part,
                                                    int ksplit) {
    const int tid  = threadIdx.x;
    const int wave = tid >> 6;
    const int lane = tid & 63;
    const int tb   = blockIdx.x & 63;   // token block (0..63), 256 tokens each
    const int ks   = blockIdx.x >> 6;   // k-split index
    const int t    = tb * 256 + wave * 64 + lane;

    const int klen = DIM / ksplit;
    const int k0   = ks * klen;
    const int k1   = k0 + klen;

    const float* __restrict__ xrow = x + (size_t)t * DIM;

    float acc[NEXP];
#pragma unroll
    for (int e = 0; e < NEXP; ++e) acc[e] = 0.f;

    for (int kk = k0; kk < k1; kk += 16) {
        const float4 a0 = *(const float4*)(xrow + kk);
        const float4 a1 = *(const float4*)(xrow + kk + 4);
        const float4 a2 = *(const float4*)(xrow + kk + 8);
        const float4 a3 = *(const float4*)(xrow + kk + 12);
        float xv[16];
        xv[0]  = a0.x; xv[1]  = a0.y; xv[2]  = a0.z; xv[3]  = a0.w;
        xv[4]  = a1.x; xv[5]  = a1.y; xv[6]  = a1.z; xv[7]  = a1.w;
        xv[8]  = a2.x; xv[9]  = a2.y; xv[10] = a2.z; xv[11] = a2.w;
        xv[12] = a3.x; xv[13] = a3.y; xv[14] = a3.z; xv[15] = a3.w;
#pragma unroll
        for (int e = 0; e < NEXP; ++e) {
            const float* __restrict__ wr = W + (size_t)e * DIM + kk;  // uniform addr
#pragma unroll
            for (int j = 0; j < 16; ++j) acc[e] = fmaf(xv[j], wr[j], acc[e]);
        }
    }

    float* __restrict__ p = part + ((size_t)ks * NTOK + t) * NEXP;
#pragma unroll
    for (int e = 0; e < NEXP; ++e) p[e] = acc[e];
}

// ---------------------------------------------------------------------------
// Kernel 2: reduce K-split partials -> logits, wave softmax (lane = expert),
// top-1 argmax (lowest-index tie-break like jnp.argmax), scatter combine
// weight, accumulate per-expert gate sums (me) and argmax counts (ce).
// grid = 512 blocks * 256 threads = 2048 waves; 8 tokens per wave.
// Partial reads: 64 consecutive floats per wave -> fully coalesced.
// ---------------------------------------------------------------------------
__global__ __launch_bounds__(256) void gate_softmax(const float* __restrict__ part,
                                                    float* __restrict__ out,
                                                    float* __restrict__ gS,
                                                    float* __restrict__ gC,
                                                    int ksplit) {
    __shared__ float smS[NEXP];
    __shared__ float smC[NEXP];
    const int tid = threadIdx.x;
    if (tid < NEXP) { smS[tid] = 0.f; smC[tid] = 0.f; }
    __syncthreads();

    const int lane = tid & 63;                       // lane = expert index
    const int wid  = blockIdx.x * 4 + (tid >> 6);    // 0..2047
    const int TPW  = NTOK / 2048;                    // 8 tokens per wave

    float meacc = 0.f, ceacc = 0.f;

    for (int i = 0; i < TPW; ++i) {
        const int t = wid * TPW + i;
        float logit = 0.f;
        for (int ks = 0; ks < ksplit; ++ks)
            logit += part[((size_t)ks * NTOK + t) * NEXP + lane];

        // wave max + argmax (prefer lower index on exact tie)
        float m = logit; int mi = lane;
#pragma unroll
        for (int off = 32; off; off >>= 1) {
            float om = __shfl_xor(m, off);
            int   oi = __shfl_xor(mi, off);
            if (om > m || (om == m && oi < mi)) { m = om; mi = oi; }
        }
        const float ex = __expf(logit - m);
        float s = ex;
#pragma unroll
        for (int off = 32; off; off >>= 1) s += __shfl_xor(s, off);

        const float gate = ex / s;
        meacc += gate;
        if (lane == mi) {
            ceacc += 1.f;
            // combine_weights[E,T]: top-1 prob = exp(m-m)/s = 1/s
            out[1 + (size_t)lane * NTOK + t] = 1.f / s;
        }
    }

    atomicAdd(&smS[lane], meacc);
    atomicAdd(&smC[lane], ceacc);
    __syncthreads();
    if (tid < NEXP) {
        atomicAdd(&gS[tid], smS[tid]);
        atomicAdd(&gC[tid], smC[tid]);
    }
}

// ---------------------------------------------------------------------------
// Kernel 3: l_aux = E * sum_e (S[e]/T)*(C[e]/T)
// ---------------------------------------------------------------------------
__global__ void gate_laux(const float* __restrict__ gS,
                          const float* __restrict__ gC,
                          float* __restrict__ out) {
    const int lane = threadIdx.x;  // 64 threads
    float v = gS[lane] * gC[lane];
#pragma unroll
    for (int off = 32; off; off >>= 1) v += __shfl_xor(v, off);
    if (lane == 0)
        out[0] = v * (float)NEXP / ((float)NTOK * (float)NTOK);
}

extern "C" void kernel_launch(void* const* d_in, const int* in_sizes, int n_in,
                              void* d_out, int out_size, void* d_ws, size_t ws_size,
                              hipStream_t stream) {
    const float* x = (const float*)d_in[0];
    const float* W = (const float*)d_in[1];
    float* out = (float*)d_out;

    // workspace layout: [0,256B) gS (64 f32), [256B,512B) gC (64 f32),
    // [512B, ...) fp32 logit partials [ksplit][NTOK][NEXP]
    float* gS   = (float*)d_ws;
    float* gC   = gS + 64;
    float* part = (float*)((char*)d_ws + 512);

    int ksplit = 8;
    while (ksplit > 1 &&
           512 + (size_t)ksplit * NTOK * NEXP * sizeof(float) > ws_size)
        ksplit >>= 1;

    // zero combine weights (+ l_aux slot) and the global accumulators
    hipMemsetAsync(d_out, 0, (size_t)out_size * sizeof(float), stream);
    hipMemsetAsync(d_ws, 0, 512, stream);

    gate_gemm<<<dim3(64 * ksplit), 256, 0, stream>>>(x, W, part, ksplit);
    gate_softmax<<<dim3(512), 256, 0, stream>>>(part, out, gS, gC, ksplit);
    gate_laux<<<1, 64, 0, stream>>>(gS, gC, out);
}

// Round 3
// 672.487 us; speedup vs baseline: 1.6290x; 1.6290x over previous
//
#include <hip/hip_runtime.h>
#include <hip/hip_bf16.h>

#define NTOK 16384
#define DIM  4096
#define NEXP 64
#define EPW  16   // experts per wave (4 waves cover 64 experts)

// ---------------------------------------------------------------------------
// Kernel 1: partial GEMM. lane = token, wave = expert-group of 16.
// acc[16]/lane stays in VGPRs (guaranteed small unroll -> no scratch demotion,
// which was the Round-2 killer: VGPR=52 + 77MB scratch traffic).
// W addresses forced wave-uniform via readfirstlane -> scalar (s_load) pipe.
// x: each lane streams its token row; 4 waves of a block share the same 64
// token rows -> L1 reuse. Block covers 64 tokens x 64 experts.
// grid = 256 token-blocks * ksplit.
// ---------------------------------------------------------------------------
__global__ __launch_bounds__(256) void gate_gemm(const float* __restrict__ x,
                                                 const float* __restrict__ W,
                                                 float* __restrict__ part,
                                                 int ksplit) {
    const int tid  = threadIdx.x;
    const int lane = tid & 63;
    const int wave = tid >> 6;                 // 0..3 -> expert group
    const int tb   = blockIdx.x & 255;         // token block (64 tokens each)
    const int ks   = blockIdx.x >> 8;          // k-split index
    const int t    = tb * 64 + lane;

    // force wave-uniform expert base into SGPR so W loads scalarize
    const int e0 = __builtin_amdgcn_readfirstlane(wave * EPW);

    const int klen = DIM / ksplit;
    const int k0   = ks * klen;
    const int k1   = k0 + klen;

    const float* __restrict__ xrow  = x + (size_t)t * DIM;
    const float* __restrict__ wbase = W + (size_t)e0 * DIM;

    float acc[EPW];
#pragma unroll
    for (int e = 0; e < EPW; ++e) acc[e] = 0.f;

    for (int kk = k0; kk < k1; kk += 16) {
        const float4 a0 = *(const float4*)(xrow + kk);
        const float4 a1 = *(const float4*)(xrow + kk + 4);
        const float4 a2 = *(const float4*)(xrow + kk + 8);
        const float4 a3 = *(const float4*)(xrow + kk + 12);
        float xv[16];
        xv[0]  = a0.x; xv[1]  = a0.y; xv[2]  = a0.z; xv[3]  = a0.w;
        xv[4]  = a1.x; xv[5]  = a1.y; xv[6]  = a1.z; xv[7]  = a1.w;
        xv[8]  = a2.x; xv[9]  = a2.y; xv[10] = a2.z; xv[11] = a2.w;
        xv[12] = a3.x; xv[13] = a3.y; xv[14] = a3.z; xv[15] = a3.w;
#pragma unroll
        for (int e = 0; e < EPW; ++e) {
            const float* __restrict__ wr = wbase + (size_t)e * DIM + kk; // uniform
#pragma unroll
            for (int j = 0; j < 16; ++j) acc[e] = fmaf(xv[j], wr[j], acc[e]);
        }
    }

    // lane writes 16 contiguous floats (one 64B line) -> fully coalesced
    float* __restrict__ p = part + ((size_t)ks * NTOK + t) * NEXP + e0;
    *(float4*)(p + 0)  = make_float4(acc[0],  acc[1],  acc[2],  acc[3]);
    *(float4*)(p + 4)  = make_float4(acc[4],  acc[5],  acc[6],  acc[7]);
    *(float4*)(p + 8)  = make_float4(acc[8],  acc[9],  acc[10], acc[11]);
    *(float4*)(p + 12) = make_float4(acc[12], acc[13], acc[14], acc[15]);
}

// ---------------------------------------------------------------------------
// Kernel 2: reduce K-split partials -> logits, wave softmax (lane = expert),
// top-1 argmax (lowest-index tie-break like jnp.argmax), scatter combine
// weight, accumulate per-expert gate sums (me) and argmax counts (ce).
// grid = 512 blocks * 256 threads = 2048 waves; 8 tokens per wave.
// ---------------------------------------------------------------------------
__global__ __launch_bounds__(256) void gate_softmax(const float* __restrict__ part,
                                                    float* __restrict__ out,
                                                    float* __restrict__ gS,
                                                    float* __restrict__ gC,
                                                    int ksplit) {
    __shared__ float smS[NEXP];
    __shared__ float smC[NEXP];
    const int tid = threadIdx.x;
    if (tid < NEXP) { smS[tid] = 0.f; smC[tid] = 0.f; }
    __syncthreads();

    const int lane = tid & 63;                       // lane = expert index
    const int wid  = blockIdx.x * 4 + (tid >> 6);    // 0..2047
    const int TPW  = NTOK / 2048;                    // 8 tokens per wave

    float meacc = 0.f, ceacc = 0.f;

    for (int i = 0; i < TPW; ++i) {
        const int t = wid * TPW + i;
        float logit = 0.f;
        for (int ks = 0; ks < ksplit; ++ks)
            logit += part[((size_t)ks * NTOK + t) * NEXP + lane];

        // wave max + argmax (prefer lower index on exact tie)
        float m = logit; int mi = lane;
#pragma unroll
        for (int off = 32; off; off >>= 1) {
            float om = __shfl_xor(m, off);
            int   oi = __shfl_xor(mi, off);
            if (om > m || (om == m && oi < mi)) { m = om; mi = oi; }
        }
        const float ex = __expf(logit - m);
        float s = ex;
#pragma unroll
        for (int off = 32; off; off >>= 1) s += __shfl_xor(s, off);

        const float gate = ex / s;
        meacc += gate;
        if (lane == mi) {
            ceacc += 1.f;
            // combine_weights[E,T]: top-1 prob = exp(m-m)/s = 1/s
            out[1 + (size_t)lane * NTOK + t] = 1.f / s;
        }
    }

    atomicAdd(&smS[lane], meacc);
    atomicAdd(&smC[lane], ceacc);
    __syncthreads();
    if (tid < NEXP) {
        atomicAdd(&gS[tid], smS[tid]);
        atomicAdd(&gC[tid], smC[tid]);
    }
}

// ---------------------------------------------------------------------------
// Kernel 3: l_aux = E * sum_e (S[e]/T)*(C[e]/T)
// ---------------------------------------------------------------------------
__global__ void gate_laux(const float* __restrict__ gS,
                          const float* __restrict__ gC,
                          float* __restrict__ out) {
    const int lane = threadIdx.x;  // 64 threads
    float v = gS[lane] * gC[lane];
#pragma unroll
    for (int off = 32; off; off >>= 1) v += __shfl_xor(v, off);
    if (lane == 0)
        out[0] = v * (float)NEXP / ((float)NTOK * (float)NTOK);
}

extern "C" void kernel_launch(void* const* d_in, const int* in_sizes, int n_in,
                              void* d_out, int out_size, void* d_ws, size_t ws_size,
                              hipStream_t stream) {
    const float* x = (const float*)d_in[0];
    const float* W = (const float*)d_in[1];
    float* out = (float*)d_out;

    // workspace layout: [0,256B) gS (64 f32), [256B,512B) gC (64 f32),
    // [512B, ...) fp32 logit partials [ksplit][NTOK][NEXP]
    float* gS   = (float*)d_ws;
    float* gC   = gS + 64;
    float* part = (float*)((char*)d_ws + 512);

    int ksplit = 4;   // 1024 blocks -> 16 waves/CU; partials 16 MB
    while (ksplit > 1 &&
           512 + (size_t)ksplit * NTOK * NEXP * sizeof(float) > ws_size)
        ksplit >>= 1;

    // zero combine weights (+ l_aux slot) and the global accumulators
    hipMemsetAsync(d_out, 0, (size_t)out_size * sizeof(float), stream);
    hipMemsetAsync(d_ws, 0, 512, stream);

    gate_gemm<<<dim3(256 * ksplit), 256, 0, stream>>>(x, W, part, ksplit);
    gate_softmax<<<dim3(512), 256, 0, stream>>>(part, out, gS, gC, ksplit);
    gate_laux<<<1, 64, 0, stream>>>(gS, gC, out);
}

// Round 4
// 535.611 us; speedup vs baseline: 2.0453x; 1.2556x over previous
//
#include <hip/hip_runtime.h>

#define NTOK 16384
#define DIM  4096
#define NEXP 64
#define SMBLK 1024   // softmax blocks

typedef __attribute__((ext_vector_type(8))) short bf16x8;
typedef __attribute__((ext_vector_type(4))) float f32x4;

__device__ __forceinline__ unsigned short f2bf(float f) {
    unsigned u = __float_as_uint(f);
    u += 0x7fffu + ((u >> 16) & 1u);           // RNE
    return (unsigned short)(u >> 16);
}
__device__ __forceinline__ float bf2f(unsigned short h) {
    return __uint_as_float((unsigned)h << 16);
}

// ---------------------------------------------------------------------------
// Kernel 0: split W fp32 -> bf16 hi + lo (1 MB total, stays L2-resident).
// ---------------------------------------------------------------------------
__global__ __launch_bounds__(256) void wsplit(const float* __restrict__ W,
                                              unsigned short* __restrict__ Whi,
                                              unsigned short* __restrict__ Wlo) {
    const int i = (blockIdx.x * 256 + threadIdx.x) * 4;
    const float4 w = *(const float4*)(W + i);
    ushort4 h, l;
    h.x = f2bf(w.x); l.x = f2bf(w.x - bf2f(h.x));
    h.y = f2bf(w.y); l.y = f2bf(w.y - bf2f(h.y));
    h.z = f2bf(w.z); l.z = f2bf(w.z - bf2f(h.z));
    h.w = f2bf(w.w); l.w = f2bf(w.w - bf2f(h.w));
    *(ushort4*)(Whi + i) = h;
    *(ushort4*)(Wlo + i) = l;
}

// ---------------------------------------------------------------------------
// Kernel 1: logits via bf16x3 MFMA (xh*wh + xh*wl + xl*wh), fp32 accum.
// Block = 4 waves x 16 tokens = 64 tokens, all 64 experts, k-slice.
// A-frag: row=lane&15 (token), k=(lane>>4)*8+j -> 2x float4 per step, convert
// in-register. B-frag: col=lane&15 (expert row of W), same k -> one 16B load.
// C/D: col=lane&15, row=(lane>>4)*4+reg (m89-verified).
// ---------------------------------------------------------------------------
__global__ __launch_bounds__(256) void gate_gemm(const float* __restrict__ x,
                                                 const unsigned short* __restrict__ Whi,
                                                 const unsigned short* __restrict__ Wlo,
                                                 float* __restrict__ part,
                                                 int ksplit) {
    const int tid   = threadIdx.x;
    const int lane  = tid & 63;
    const int wv    = tid >> 6;
    const int tb    = blockIdx.x & 255;
    const int ks    = blockIdx.x >> 8;
    const int klen  = DIM / ksplit;
    const int k0    = ks * klen;
    const int tbase = tb * 64 + wv * 16;
    const int row   = lane & 15;
    const int kj    = (lane >> 4) * 8;

    const float*          xrow = x   + (size_t)(tbase + row) * DIM + k0 + kj;
    const unsigned short* whr  = Whi + (size_t)row * DIM + k0 + kj;
    const unsigned short* wlr  = Wlo + (size_t)row * DIM + k0 + kj;

    f32x4 acc[4];
#pragma unroll
    for (int c = 0; c < 4; ++c) acc[c] = (f32x4){0.f, 0.f, 0.f, 0.f};

    for (int kk = 0; kk < klen; kk += 32) {
        const float4 xa = *(const float4*)(xrow + kk);
        const float4 xb = *(const float4*)(xrow + kk + 4);
        bf16x8 ah, al;
        {
            float f; unsigned short h;
            f = xa.x; h = f2bf(f); ah[0] = (short)h; al[0] = (short)f2bf(f - bf2f(h));
            f = xa.y; h = f2bf(f); ah[1] = (short)h; al[1] = (short)f2bf(f - bf2f(h));
            f = xa.z; h = f2bf(f); ah[2] = (short)h; al[2] = (short)f2bf(f - bf2f(h));
            f = xa.w; h = f2bf(f); ah[3] = (short)h; al[3] = (short)f2bf(f - bf2f(h));
            f = xb.x; h = f2bf(f); ah[4] = (short)h; al[4] = (short)f2bf(f - bf2f(h));
            f = xb.y; h = f2bf(f); ah[5] = (short)h; al[5] = (short)f2bf(f - bf2f(h));
            f = xb.z; h = f2bf(f); ah[6] = (short)h; al[6] = (short)f2bf(f - bf2f(h));
            f = xb.w; h = f2bf(f); ah[7] = (short)h; al[7] = (short)f2bf(f - bf2f(h));
        }
#pragma unroll
        for (int c = 0; c < 4; ++c) {
            const bf16x8 bh = *(const bf16x8*)(whr + (size_t)c * 16 * DIM + kk);
            const bf16x8 bl = *(const bf16x8*)(wlr + (size_t)c * 16 * DIM + kk);
            acc[c] = __builtin_amdgcn_mfma_f32_16x16x32_bf16(ah, bh, acc[c], 0, 0, 0);
            acc[c] = __builtin_amdgcn_mfma_f32_16x16x32_bf16(ah, bl, acc[c], 0, 0, 0);
            acc[c] = __builtin_amdgcn_mfma_f32_16x16x32_bf16(al, bh, acc[c], 0, 0, 0);
        }
    }

    const int r0 = (lane >> 4) * 4;
    float* p = part + ((size_t)ks * NTOK + tbase + r0) * NEXP + (lane & 15);
#pragma unroll
    for (int c = 0; c < 4; ++c)
#pragma unroll
        for (int r = 0; r < 4; ++r)
            p[(size_t)r * NEXP + c * 16] = acc[c][r];
}

// ---------------------------------------------------------------------------
// Kernel 2: reduce k-split partials -> logits, wave softmax (lane = expert),
// top-1 argmax (low-index tie-break), scatter combine weight, per-BLOCK
// me/ce partial sums written to ws (no global atomics).
// ---------------------------------------------------------------------------
template <int KSPLIT>
__global__ __launch_bounds__(256) void gate_softmax(const float* __restrict__ part,
                                                    float* __restrict__ out,
                                                    float* __restrict__ gSp,
                                                    float* __restrict__ gCp) {
    __shared__ float smS[NEXP];
    __shared__ float smC[NEXP];
    const int tid = threadIdx.x;
    if (tid < NEXP) { smS[tid] = 0.f; smC[tid] = 0.f; }
    __syncthreads();

    const int lane = tid & 63;                        // lane = expert
    const int wid  = blockIdx.x * 4 + (tid >> 6);
    const int TPW  = NTOK / (SMBLK * 4);

    float meacc = 0.f, ceacc = 0.f;

    for (int i = 0; i < TPW; ++i) {
        const int t = wid * TPW + i;
        float logit = 0.f;
#pragma unroll
        for (int ks = 0; ks < KSPLIT; ++ks)
            logit += part[((size_t)ks * NTOK + t) * NEXP + lane];

        float m = logit; int mi = lane;
#pragma unroll
        for (int off = 32; off; off >>= 1) {
            float om = __shfl_xor(m, off);
            int   oi = __shfl_xor(mi, off);
            if (om > m || (om == m && oi < mi)) { m = om; mi = oi; }
        }
        const float ex = __expf(logit - m);
        float s = ex;
#pragma unroll
        for (int off = 32; off; off >>= 1) s += __shfl_xor(s, off);

        meacc += ex / s;
        if (lane == mi) {
            ceacc += 1.f;
            out[1 + (size_t)lane * NTOK + t] = 1.f / s;   // top1 prob = 1/s
        }
    }

    atomicAdd(&smS[lane], meacc);
    atomicAdd(&smC[lane], ceacc);
    __syncthreads();
    if (tid < NEXP) {
        gSp[blockIdx.x * NEXP + tid] = smS[tid];
        gCp[blockIdx.x * NEXP + tid] = smC[tid];
    }
}

// ---------------------------------------------------------------------------
// Kernel 3: reduce per-block partials, l_aux = E * sum_e S_e*C_e / T^2
// ---------------------------------------------------------------------------
__global__ __launch_bounds__(256) void gate_laux(const float* __restrict__ gSp,
                                                 const float* __restrict__ gCp,
                                                 float* __restrict__ out) {
    __shared__ float sS[NEXP];
    __shared__ float sC[NEXP];
    const int tid = threadIdx.x;
    if (tid < NEXP) { sS[tid] = 0.f; sC[tid] = 0.f; }
    __syncthreads();

    float accS = 0.f, accC = 0.f;
    for (int i = tid; i < SMBLK * NEXP; i += 256) {  // e = i&63 = tid&63 const
        accS += gSp[i];
        accC += gCp[i];
    }
    atomicAdd(&sS[tid & 63], accS);
    atomicAdd(&sC[tid & 63], accC);
    __syncthreads();

    if (tid < NEXP) {
        float v = sS[tid] * sC[tid];
#pragma unroll
        for (int off = 32; off; off >>= 1) v += __shfl_xor(v, off);
        if (tid == 0)
            out[0] = v * (float)NEXP / ((float)NTOK * (float)NTOK);
    }
}

extern "C" void kernel_launch(void* const* d_in, const int* in_sizes, int n_in,
                              void* d_out, int out_size, void* d_ws, size_t ws_size,
                              hipStream_t stream) {
    const float* x = (const float*)d_in[0];
    const float* W = (const float*)d_in[1];
    float* out = (float*)d_out;

    // ws layout:
    //   gSp  [SMBLK*64] f32          256 KB
    //   gCp  [SMBLK*64] f32          256 KB
    //   Whi  [64*4096]  u16          512 KB
    //   Wlo  [64*4096]  u16          512 KB
    //   part [ksplit][NTOK][NEXP] f32
    char* base = (char*)d_ws;
    float*          gSp  = (float*)base;
    float*          gCp  = (float*)(base + (size_t)SMBLK * NEXP * 4);
    unsigned short* Whi  = (unsigned short*)(base + 2 * (size_t)SMBLK * NEXP * 4);
    unsigned short* Wlo  = Whi + (size_t)NEXP * DIM;
    const size_t    head = 2 * (size_t)SMBLK * NEXP * 4 + 2 * (size_t)NEXP * DIM * 2;
    float*          part = (float*)(base + head);

    int ksplit = 8;
    while (ksplit > 1 &&
           head + (size_t)ksplit * NTOK * NEXP * sizeof(float) > ws_size)
        ksplit >>= 1;

    hipMemsetAsync(d_out, 0, (size_t)out_size * sizeof(float), stream);

    wsplit<<<dim3((NEXP * DIM) / 1024), 256, 0, stream>>>(W, Whi, Wlo);
    gate_gemm<<<dim3(256 * ksplit), 256, 0, stream>>>(x, Whi, Wlo, part, ksplit);
    if (ksplit == 8)
        gate_softmax<8><<<dim3(SMBLK), 256, 0, stream>>>(part, out, gSp, gCp);
    else if (ksplit == 4)
        gate_softmax<4><<<dim3(SMBLK), 256, 0, stream>>>(part, out, gSp, gCp);
    else if (ksplit == 2)
        gate_softmax<2><<<dim3(SMBLK), 256, 0, stream>>>(part, out, gSp, gCp);
    else
        gate_softmax<1><<<dim3(SMBLK), 256, 0, stream>>>(part, out, gSp, gCp);
    gate_laux<<<dim3(1), 256, 0, stream>>>(gSp, gCp, out);
}

// Round 6
// 437.056 us; speedup vs baseline: 2.5065x; 1.2255x over previous
//
#include <hip/hip_runtime.h>
#include <hip/hip_bf16.h>

#define NTOK   16384
#define DIM    4096
#define NEXP   64
#define KSPLIT 8
#define KLEN   (DIM / KSPLIT)   // 512
#define BM     256              // tokens per block (4 waves x 64)
#define KSTEP  32
#define SMBLK  256              // softmax blocks

typedef __attribute__((ext_vector_type(8))) short bf16x8;
typedef __attribute__((ext_vector_type(4))) float f32x4;

__device__ __forceinline__ unsigned short f2bf(float f) {
    unsigned u = __float_as_uint(f);
    u += 0x7fffu + ((u >> 16) & 1u);           // RNE
    return (unsigned short)(u >> 16);
}
__device__ __forceinline__ float bf2f(unsigned short h) {
    return __uint_as_float((unsigned)h << 16);
}

// ---------------------------------------------------------------------------
// Kernel 0: split W fp32 -> bf16 hi/lo in MFMA B-fragment order.
// Wf[kb][eb][hl][lane][8] bf16 ; lane holds W[eb*16+(lane&15)][kb*32+(lane>>4)*8+j]
// -> gemm's B loads are fully coalesced 1KB dwordx4 (L2-resident, 1MB total).
// ---------------------------------------------------------------------------
__global__ __launch_bounds__(256) void wsplit(const float* __restrict__ W,
                                              unsigned short* __restrict__ Wf) {
    const int s    = blockIdx.x * 256 + threadIdx.x;   // 32768 threads
    const int lane = s & 63;
    const int eb   = (s >> 6) & 3;
    const int kb   = s >> 8;                           // 0..127
    const int e    = eb * 16 + (lane & 15);
    const int k8   = kb * 4 + (lane >> 4);             // 8-float group

    const float4 w0 = *(const float4*)(W + (size_t)e * DIM + k8 * 8);
    const float4 w1 = *(const float4*)(W + (size_t)e * DIM + k8 * 8 + 4);
    float f[8] = {w0.x, w0.y, w0.z, w0.w, w1.x, w1.y, w1.z, w1.w};

    unsigned short hi[8], lo[8];
#pragma unroll
    for (int j = 0; j < 8; ++j) {
        hi[j] = f2bf(f[j]);
        lo[j] = f2bf(f[j] - bf2f(hi[j]));
    }
    const size_t fbase = ((size_t)(kb * 4 + eb) * 2) * 512;  // ushort units
    ushort4* ph = (ushort4*)(Wf + fbase + lane * 8);
    ushort4* pl = (ushort4*)(Wf + fbase + 512 + lane * 8);
    ph[0] = make_ushort4(hi[0], hi[1], hi[2], hi[3]);
    ph[1] = make_ushort4(hi[4], hi[5], hi[6], hi[7]);
    pl[0] = make_ushort4(lo[0], lo[1], lo[2], lo[3]);
    pl[1] = make_ushort4(lo[4], lo[5], lo[6], lo[7]);
}

// ---------------------------------------------------------------------------
// Kernel 1: bf16x3 MFMA GEMM, LDS-staged x (XOR-swizzled), fragment-order W.
// Block = 256 tokens x 64 experts x k-slice (KLEN). Wave = 64 tokens.
// Staging: coalesced global float4 -> regs (issued early, T14) -> ds_write
// swizzled -> ds_read_b128 fragments (2-way banks = free).
// ---------------------------------------------------------------------------
__global__ __launch_bounds__(256, 2) void gate_gemm(const float* __restrict__ x,
                                                    const unsigned short* __restrict__ Wf,
                                                    float* __restrict__ part) {
    __shared__ float xt[BM * KSTEP];   // 32KB: [token][chunk ^ (token&7)]

    const int tid  = threadIdx.x;
    const int lane = tid & 63;
    const int wv   = tid >> 6;
    const int tb   = blockIdx.x & 63;       // token block
    const int ks   = blockIdx.x >> 6;       // k slice
    const int k0   = ks * KLEN;

    const int g = lane >> 3;                // staging: row-in-group 0..7
    const int c = lane & 7;                 // staging: 16B chunk 0..7
    const int tw = wv * 64;                 // wave's token base (relative)

    // ---- prologue: load tile kk=0 into regs (coalesced: 8x128B per instr)
    float4 st[8];
#pragma unroll
    for (int i = 0; i < 8; ++i)
        st[i] = *(const float4*)(x + (size_t)(tb * BM + tw + i * 8 + g) * DIM + k0 + c * 4);

    f32x4 acc[4][4];
#pragma unroll
    for (int f = 0; f < 4; ++f)
#pragma unroll
        for (int eb = 0; eb < 4; ++eb) acc[f][eb] = (f32x4){0.f, 0.f, 0.f, 0.f};

    for (int kk = 0; kk < KLEN; kk += KSTEP) {
        // ---- write staged tile to LDS, swizzled: chunk' = chunk ^ (token&7)
#pragma unroll
        for (int i = 0; i < 8; ++i) {
            const int t = tw + i * 8 + g;            // t&7 == g
            *(float4*)&xt[(size_t)t * KSTEP + ((c ^ g) * 4)] = st[i];
        }
        __syncthreads();

        // ---- T14: issue NEXT tile's global loads now; they complete under MFMA
        if (kk + KSTEP < KLEN) {
#pragma unroll
            for (int i = 0; i < 8; ++i)
                st[i] = *(const float4*)(x + (size_t)(tb * BM + tw + i * 8 + g) * DIM
                                         + k0 + kk + KSTEP + c * 4);
        }

        // ---- B fragments: coalesced 1KB loads from L2
        const int kb = (k0 + kk) >> 5;
        bf16x8 bh[4], bl[4];
#pragma unroll
        for (int eb = 0; eb < 4; ++eb) {
            const size_t fbase = ((size_t)(kb * 4 + eb) * 2) * 512;
            bh[eb] = *(const bf16x8*)(Wf + fbase + lane * 8);
            bl[eb] = *(const bf16x8*)(Wf + fbase + 512 + lane * 8);
        }

        // ---- A fragments from LDS + bf16 hi/lo split + MFMA
#pragma unroll
        for (int f = 0; f < 4; ++f) {
            const int tf = tw + f * 16 + (lane & 15);
            const int c2 = (lane >> 4) * 2;
            const int t7 = tf & 7;
            const float4 xa = *(const float4*)&xt[(size_t)tf * KSTEP + ((c2 ^ t7) * 4)];
            const float4 xb = *(const float4*)&xt[(size_t)tf * KSTEP + (((c2 + 1) ^ t7) * 4)];
            float fv[8] = {xa.x, xa.y, xa.z, xa.w, xb.x, xb.y, xb.z, xb.w};
            bf16x8 ah, al;
#pragma unroll
            for (int j = 0; j < 8; ++j) {
                const __hip_bfloat16 h = __float2bfloat16(fv[j]);
                const __hip_bfloat16 l = __float2bfloat16(fv[j] - __bfloat162float(h));
                ah[j] = *(const short*)&h;
                al[j] = *(const short*)&l;
            }
#pragma unroll
            for (int eb = 0; eb < 4; ++eb) {
                acc[f][eb] = __builtin_amdgcn_mfma_f32_16x16x32_bf16(ah, bh[eb], acc[f][eb], 0, 0, 0);
                acc[f][eb] = __builtin_amdgcn_mfma_f32_16x16x32_bf16(ah, bl[eb], acc[f][eb], 0, 0, 0);
                acc[f][eb] = __builtin_amdgcn_mfma_f32_16x16x32_bf16(al, bh[eb], acc[f][eb], 0, 0, 0);
            }
        }
        __syncthreads();
    }

    // ---- partial write: C/D col=lane&15, row=(lane>>4)*4+r (m89-verified)
    const int r0 = (lane >> 4) * 4;
#pragma unroll
    for (int f = 0; f < 4; ++f) {
        float* p = part + ((size_t)ks * NTOK + tb * BM + tw + f * 16 + r0) * NEXP + (lane & 15);
#pragma unroll
        for (int eb = 0; eb < 4; ++eb)
#pragma unroll
            for (int r = 0; r < 4; ++r)
                p[(size_t)r * NEXP + eb * 16] = acc[f][eb][r];
    }
}

// ---------------------------------------------------------------------------
// Kernel 2: reduce k-split partials -> logits, wave softmax (lane = expert),
// top-1 argmax (low-index tie-break), scatter combine weight, per-block
// me/ce partials to ws.  256 blocks * 4 waves * 16 tokens = 16384.
// ---------------------------------------------------------------------------
__global__ __launch_bounds__(256) void gate_softmax(const float* __restrict__ part,
                                                    float* __restrict__ out,
                                                    float* __restrict__ gSp,
                                                    float* __restrict__ gCp) {
    __shared__ float smS[NEXP];
    __shared__ float smC[NEXP];
    const int tid = threadIdx.x;
    if (tid < NEXP) { smS[tid] = 0.f; smC[tid] = 0.f; }
    __syncthreads();

    const int lane = tid & 63;                        // lane = expert
    const int wid  = blockIdx.x * 4 + (tid >> 6);
    const int TPW  = NTOK / (SMBLK * 4);              // 16

    float meacc = 0.f, ceacc = 0.f;

    for (int i = 0; i < TPW; ++i) {
        const int t = wid * TPW + i;
        float logit = 0.f;
#pragma unroll
        for (int ks = 0; ks < KSPLIT; ++ks)
            logit += part[((size_t)ks * NTOK + t) * NEXP + lane];

        float m = logit; int mi = lane;
#pragma unroll
        for (int off = 32; off; off >>= 1) {
            float om = __shfl_xor(m, off);
            int   oi = __shfl_xor(mi, off);
            if (om > m || (om == m && oi < mi)) { m = om; mi = oi; }
        }
        const float ex = __expf(logit - m);
        float s = ex;
#pragma unroll
        for (int off = 32; off; off >>= 1) s += __shfl_xor(s, off);

        meacc += ex / s;
        if (lane == mi) {
            ceacc += 1.f;
            out[1 + (size_t)lane * NTOK + t] = 1.f / s;   // top1 prob = 1/s
        }
    }

    atomicAdd(&smS[lane], meacc);
    atomicAdd(&smC[lane], ceacc);
    __syncthreads();
    if (tid < NEXP) {
        gSp[blockIdx.x * NEXP + tid] = smS[tid];
        gCp[blockIdx.x * NEXP + tid] = smC[tid];
    }
}

// ---------------------------------------------------------------------------
// Kernel 3: reduce per-block partials, l_aux = E * sum_e S_e*C_e / T^2.
// 1024 threads, 16 waves -> decent ILP/BW on the 128KB of partials.
// ---------------------------------------------------------------------------
__global__ __launch_bounds__(1024) void gate_laux(const float* __restrict__ gSp,
                                                  const float* __restrict__ gCp,
                                                  float* __restrict__ out) {
    __shared__ float sS[NEXP];
    __shared__ float sC[NEXP];
    const int tid = threadIdx.x;
    if (tid < NEXP) { sS[tid] = 0.f; sC[tid] = 0.f; }
    __syncthreads();

    float accS = 0.f, accC = 0.f;
    for (int i = tid; i < SMBLK * NEXP; i += 1024) {   // e = i&63 = tid&63 const
        accS += gSp[i];
        accC += gCp[i];
    }
    atomicAdd(&sS[tid & 63], accS);
    atomicAdd(&sC[tid & 63], accC);
    __syncthreads();

    if (tid < NEXP) {
        float v = sS[tid] * sC[tid];
#pragma unroll
        for (int off = 32; off; off >>= 1) v += __shfl_xor(v, off);
        if (tid == 0)
            out[0] = v * (float)NEXP / ((float)NTOK * (float)NTOK);
    }
}

extern "C" void kernel_launch(void* const* d_in, const int* in_sizes, int n_in,
                              void* d_out, int out_size, void* d_ws, size_t ws_size,
                              hipStream_t stream) {
    const float* x = (const float*)d_in[0];
    const float* W = (const float*)d_in[1];
    float* out = (float*)d_out;

    // ws layout:
    //   gSp  [SMBLK*64] f32      64 KB
    //   gCp  [SMBLK*64] f32      64 KB
    //   Wf   [128*4*2*512] u16   1 MB   (fragment-ordered bf16 hi/lo)
    //   part [KSPLIT][NTOK][NEXP] f32   32 MB
    char* base = (char*)d_ws;
    float*          gSp  = (float*)base;
    float*          gCp  = (float*)(base + (size_t)SMBLK * NEXP * 4);
    unsigned short* Wf   = (unsigned short*)(base + 2 * (size_t)SMBLK * NEXP * 4);
    float*          part = (float*)(base + 2 * (size_t)SMBLK * NEXP * 4
                                    + (size_t)128 * 4 * 2 * 512 * 2);

    hipMemsetAsync(d_out, 0, (size_t)out_size * sizeof(float), stream);

    wsplit<<<dim3(128), 256, 0, stream>>>(W, Wf);
    gate_gemm<<<dim3(64 * KSPLIT), 256, 0, stream>>>(x, Wf, part);
    gate_softmax<<<dim3(SMBLK), 256, 0, stream>>>(part, out, gSp, gCp);
    gate_laux<<<dim3(1), 1024, 0, stream>>>(gSp, gCp, out);
}

// Round 12
// 411.106 us; speedup vs baseline: 2.6647x; 1.0631x over previous
//
#include <hip/hip_runtime.h>
#include <hip/hip_bf16.h>

#define NTOK   16384
#define DIM    4096
#define NEXP   64
#define KSTEP  32
#define KHALF  2048
#define ITERS  (KHALF / KSTEP)   // 64
#define NBLK   256               // NTOK / 64

typedef __attribute__((ext_vector_type(8))) short bf16x8;
typedef __attribute__((ext_vector_type(4))) float f32x4;

__device__ __forceinline__ unsigned short f2bf(float f) {
    unsigned u = __float_as_uint(f);
    u += 0x7fffu + ((u >> 16) & 1u);           // RNE
    return (unsigned short)(u >> 16);
}
__device__ __forceinline__ float bf2f(unsigned short h) {
    return __uint_as_float((unsigned)h << 16);
}

// ---------------------------------------------------------------------------
// Kernel 0: split W fp32 -> bf16 hi/lo in MFMA B-fragment order.
// Wf[kb][eb][hl][lane][8] ; lane holds W[eb*16+(lane&15)][kb*32+(lane>>4)*8+j]
// ---------------------------------------------------------------------------
__global__ __launch_bounds__(256) void wsplit(const float* __restrict__ W,
                                              unsigned short* __restrict__ Wf) {
    const int s    = blockIdx.x * 256 + threadIdx.x;   // 32768 threads
    const int lane = s & 63;
    const int eb   = (s >> 6) & 3;
    const int kb   = s >> 8;                           // 0..127
    const int e    = eb * 16 + (lane & 15);
    const int k8   = kb * 4 + (lane >> 4);

    const float4 w0 = *(const float4*)(W + (size_t)e * DIM + k8 * 8);
    const float4 w1 = *(const float4*)(W + (size_t)e * DIM + k8 * 8 + 4);
    float f[8] = {w0.x, w0.y, w0.z, w0.w, w1.x, w1.y, w1.z, w1.w};

    unsigned short hi[8], lo[8];
#pragma unroll
    for (int j = 0; j < 8; ++j) {
        hi[j] = f2bf(f[j]);
        lo[j] = f2bf(f[j] - bf2f(hi[j]));
    }
    const size_t fbase = ((size_t)(kb * 4 + eb) * 2) * 512;  // ushort units
    ushort4* ph = (ushort4*)(Wf + fbase + lane * 8);
    ushort4* pl = (ushort4*)(Wf + fbase + 512 + lane * 8);
    ph[0] = make_ushort4(hi[0], hi[1], hi[2], hi[3]);
    ph[1] = make_ushort4(hi[4], hi[5], hi[6], hi[7]);
    pl[0] = make_ushort4(lo[0], lo[1], lo[2], lo[3]);
    pl[1] = make_ushort4(lo[4], lo[5], lo[6], lo[7]);
}

// ---------------------------------------------------------------------------
// Fused kernel: bf16x3 MFMA logits + softmax + top1 scatter + me/ce partials.
// 256 blocks x 512 threads (8 waves). wave = (wq token-quarter, kw k-half).
// Each wave: 16 tokens x 64 experts x 2048 K. Per-wave private LDS staging
// (no barriers in K-loop), 4-deep register prefetch, XOR-swizzled LDS.
// Epilogue: k-half reduce via LDS, in-register softmax (shfl over 16-lane
// groups), top1 write, me/ce into LDS -> per-block partials.
// ---------------------------------------------------------------------------
__global__ __launch_bounds__(512, 2) void gate_fused(const float* __restrict__ x,
                                                     const unsigned short* __restrict__ Wf,
                                                     float* __restrict__ out,
                                                     float* __restrict__ gSp,
                                                     float* __restrict__ gCp) {
    __shared__ float ldsx[8][2][16][32];   // 32 KB staging, per-wave [2]-dbuf
    __shared__ f32x4 red[4][4][64];        // 16 KB k-half reduction
    __shared__ float smS[NEXP];
    __shared__ float smC[NEXP];

    const int tid  = threadIdx.x;
    const int lane = tid & 63;
    const int wv   = tid >> 6;     // 0..7
    const int wq   = wv & 3;       // token quarter
    const int kw   = wv >> 2;      // k half
    const int tb   = blockIdx.x;
    const int tq   = tb * 64 + wq * 16;

    if (tid < NEXP) { smS[tid] = 0.f; smC[tid] = 0.f; }

    // staging geometry: lane -> (token row, 16B chunk), swizzle chunk^=(row&7)
    const int tokrow = lane >> 2;
    const int c0     = lane & 3;
    const int rs     = tokrow & 7;
    const int cw0    = (c0 ^ rs) * 4;
    const int cw1    = ((c0 + 4) ^ rs) * 4;
    const float* xpre = x + (size_t)(tq + tokrow) * DIM + kw * KHALF + c0 * 4;

    // fragment-read geometry
    const int tfr = lane & 15;
    const int rs2 = tfr & 7;
    const int c2  = (lane >> 4) * 2;
    const int ra  = (c2 ^ rs2) * 4;
    const int rb  = ((c2 + 1) ^ rs2) * 4;
    const int kbase = kw * ITERS;

    f32x4 acc[4];
#pragma unroll
    for (int eb = 0; eb < 4; ++eb) acc[eb] = (f32x4){0.f, 0.f, 0.f, 0.f};

    auto body = [&](float4& A, float4& B, int itc, int buf) {
        // write staged tile (swizzled)
        *(float4*)&ldsx[wv][buf][tokrow][cw0] = A;
        *(float4*)&ldsx[wv][buf][tokrow][cw1] = B;
        // prefetch 4 iters ahead
        if (itc + 4 < ITERS) {
            A = *(const float4*)(xpre + (size_t)(itc + 4) * KSTEP);
            B = *(const float4*)(xpre + (size_t)(itc + 4) * KSTEP + 16);
        }
        // A-fragment from LDS + bf16 hi/lo split
        const float4 xa = *(const float4*)&ldsx[wv][buf][tfr][ra];
        const float4 xb = *(const float4*)&ldsx[wv][buf][tfr][rb];
        const float fv[8] = {xa.x, xa.y, xa.z, xa.w, xb.x, xb.y, xb.z, xb.w};
        bf16x8 ah, al;
#pragma unroll
        for (int j = 0; j < 8; ++j) {
            const __hip_bfloat16 h = __float2bfloat16(fv[j]);
            const __hip_bfloat16 l = __float2bfloat16(fv[j] - __bfloat162float(h));
            ah[j] = *(const short*)&h;
            al[j] = *(const short*)&l;
        }
        const int kbv = kbase + itc;
#pragma unroll
        for (int eb = 0; eb < 4; ++eb) {
            const size_t fbase = ((size_t)(kbv * 4 + eb) * 2) * 512;
            const bf16x8 bh = *(const bf16x8*)(Wf + fbase + lane * 8);
            const bf16x8 bl = *(const bf16x8*)(Wf + fbase + 512 + lane * 8);
            acc[eb] = __builtin_amdgcn_mfma_f32_16x16x32_bf16(ah, bh, acc[eb], 0, 0, 0);
            acc[eb] = __builtin_amdgcn_mfma_f32_16x16x32_bf16(ah, bl, acc[eb], 0, 0, 0);
            acc[eb] = __builtin_amdgcn_mfma_f32_16x16x32_bf16(al, bh, acc[eb], 0, 0, 0);
        }
    };

    // prologue: 4-deep prefetch
    float4 s0a = *(const float4*)(xpre + 0 * KSTEP), s0b = *(const float4*)(xpre + 0 * KSTEP + 16);
    float4 s1a = *(const float4*)(xpre + 1 * KSTEP), s1b = *(const float4*)(xpre + 1 * KSTEP + 16);
    float4 s2a = *(const float4*)(xpre + 2 * KSTEP), s2b = *(const float4*)(xpre + 2 * KSTEP + 16);
    float4 s3a = *(const float4*)(xpre + 3 * KSTEP), s3b = *(const float4*)(xpre + 3 * KSTEP + 16);

    for (int it = 0; it < ITERS; it += 4) {
        body(s0a, s0b, it + 0, 0);
        body(s1a, s1b, it + 1, 1);
        body(s2a, s2b, it + 2, 0);
        body(s3a, s3b, it + 3, 1);
    }

    // ---- combine k-halves
    __syncthreads();
    if (kw == 1) {
#pragma unroll
        for (int eb = 0; eb < 4; ++eb) red[wq][eb][lane] = acc[eb];
    }
    __syncthreads();

    if (kw == 0) {
#pragma unroll
        for (int eb = 0; eb < 4; ++eb) acc[eb] += red[wq][eb][lane];

        // ---- softmax + top1 per token. lane holds logit[token=(lane>>4)*4+r]
        //      [expert=eb*16+(lane&15)]; expert dim = (eb, lane&15) -> shfl
        //      over masks 1,2,4,8 stays in the 16-lane group.
        const int col = lane & 15;
        const int G   = lane >> 4;
        float me0 = 0.f, me1 = 0.f, me2 = 0.f, me3 = 0.f;
        float ce0 = 0.f, ce1 = 0.f, ce2 = 0.f, ce3 = 0.f;

#pragma unroll
        for (int r = 0; r < 4; ++r) {
            float m = acc[0][r]; int me = col;      // ascending e: ties keep low
            if (acc[1][r] > m) { m = acc[1][r]; me = 16 + col; }
            if (acc[2][r] > m) { m = acc[2][r]; me = 32 + col; }
            if (acc[3][r] > m) { m = acc[3][r]; me = 48 + col; }
#pragma unroll
            for (int mask = 1; mask <= 8; mask <<= 1) {
                const float om = __shfl_xor(m, mask);
                const int   oe = __shfl_xor(me, mask);
                if (om > m || (om == m && oe < me)) { m = om; me = oe; }
            }
            const float e0 = __expf(acc[0][r] - m);
            const float e1 = __expf(acc[1][r] - m);
            const float e2 = __expf(acc[2][r] - m);
            const float e3 = __expf(acc[3][r] - m);
            float s = e0 + e1 + e2 + e3;
#pragma unroll
            for (int mask = 1; mask <= 8; mask <<= 1) s += __shfl_xor(s, mask);
            const float inv = 1.f / s;
            me0 += e0 * inv; me1 += e1 * inv; me2 += e2 * inv; me3 += e3 * inv;

            if (col == (me & 15)) {
                const int tok = tq + G * 4 + r;
                out[1 + (size_t)me * NTOK + tok] = inv;   // top1 prob = 1/s
                ce0 += (me >> 4) == 0 ? 1.f : 0.f;
                ce1 += (me >> 4) == 1 ? 1.f : 0.f;
                ce2 += (me >> 4) == 2 ? 1.f : 0.f;
                ce3 += (me >> 4) == 3 ? 1.f : 0.f;
            }
        }
        atomicAdd(&smS[col],      me0); atomicAdd(&smS[16 + col], me1);
        atomicAdd(&smS[32 + col], me2); atomicAdd(&smS[48 + col], me3);
        atomicAdd(&smC[col],      ce0); atomicAdd(&smC[16 + col], ce1);
        atomicAdd(&smC[32 + col], ce2); atomicAdd(&smC[48 + col], ce3);
    }
    __syncthreads();
    if (tid < NEXP) {
        gSp[(size_t)tb * NEXP + tid] = smS[tid];
        gCp[(size_t)tb * NEXP + tid] = smC[tid];
    }
}

// ---------------------------------------------------------------------------
// Kernel 2: reduce per-block partials, l_aux = E * sum_e S_e*C_e / T^2
// ---------------------------------------------------------------------------
__global__ __launch_bounds__(1024) void gate_laux(const float* __restrict__ gSp,
                                                  const float* __restrict__ gCp,
                                                  float* __restrict__ out) {
    __shared__ float sS[NEXP];
    __shared__ float sC[NEXP];
    const int tid = threadIdx.x;
    if (tid < NEXP) { sS[tid] = 0.f; sC[tid] = 0.f; }
    __syncthreads();

    float accS = 0.f, accC = 0.f;
    for (int i = tid; i < NBLK * NEXP; i += 1024) {   // e = i&63 = tid&63 const
        accS += gSp[i];
        accC += gCp[i];
    }
    atomicAdd(&sS[tid & 63], accS);
    atomicAdd(&sC[tid & 63], accC);
    __syncthreads();

    if (tid < NEXP) {
        float v = sS[tid] * sC[tid];
#pragma unroll
        for (int off = 32; off; off >>= 1) v += __shfl_xor(v, off);
        if (tid == 0)
            out[0] = v * (float)NEXP / ((float)NTOK * (float)NTOK);
    }
}

extern "C" void kernel_launch(void* const* d_in, const int* in_sizes, int n_in,
                              void* d_out, int out_size, void* d_ws, size_t ws_size,
                              hipStream_t stream) {
    const float* x = (const float*)d_in[0];
    const float* W = (const float*)d_in[1];
    float* out = (float*)d_out;

    // ws layout: gSp [256*64] f32 (64KB) | gCp (64KB) | Wf 1MB (frag-ordered)
    char* base = (char*)d_ws;
    float*          gSp = (float*)base;
    float*          gCp = (float*)(base + (size_t)NBLK * NEXP * 4);
    unsigned short* Wf  = (unsigned short*)(base + 2 * (size_t)NBLK * NEXP * 4);

    hipMemsetAsync(d_out, 0, (size_t)out_size * sizeof(float), stream);

    wsplit<<<dim3(128), 256, 0, stream>>>(W, Wf);
    gate_fused<<<dim3(NBLK), 512, 0, stream>>>(x, Wf, out, gSp, gCp);
    gate_laux<<<dim3(1), 1024, 0, stream>>>(gSp, gCp, out);
}